// Round 1
// 900.047 us; speedup vs baseline: 1.2218x; 1.2218x over previous
//
#include <hip/hip_runtime.h>
#include <stdint.h>

// ---------- types ----------
typedef __bf16 bf16x8 __attribute__((ext_vector_type(8)));
typedef float f32x4 __attribute__((ext_vector_type(4)));

#define SCALE_Q 0.125f

// fp32 -> bf16 round-to-nearest-even
__device__ __forceinline__ unsigned short f2bf(float f) {
  unsigned int u = __float_as_uint(f);
  u = (u + 0x7fffu + ((u >> 16) & 1u)) >> 16;
  return (unsigned short)u;
}

// async global->LDS, 16B per lane. LDS dest = wave-uniform base + lane*16.
__device__ __forceinline__ void gl_lds16(const unsigned short* g, unsigned short* l) {
  __builtin_amdgcn_global_load_lds(
      (const __attribute__((address_space(1))) unsigned int*)g,
      (__attribute__((address_space(3))) unsigned int*)l, 16, 0, 0);
}

__device__ __forceinline__ f32x4 mfma16(bf16x8 a, bf16x8 b, f32x4 c) {
  return __builtin_amdgcn_mfma_f32_16x16x32_bf16(a, b, c, 0, 0, 0);
}

// ---------- kernel 1: x fp32 -> bf16 ----------
__global__ void convert_x_kernel(const float* __restrict__ x, unsigned short* __restrict__ xb) {
  int i = blockIdx.x * 256 + threadIdx.x;   // one float4 per thread, exact cover
  float4 f = ((const float4*)x)[i];
  ushort4 o;
  o.x = f2bf(f.x); o.y = f2bf(f.y); o.z = f2bf(f.z); o.w = f2bf(f.w);
  ((ushort4*)xb)[i] = o;
}

// ---------- kernel 2: pack transposed bf16 weights + bias ----------
__global__ void prep_w_kernel(const float* __restrict__ Wq, const float* __restrict__ Wkv,
                              const float* __restrict__ bq, const float* __restrict__ bkv,
                              const float* __restrict__ Wp,
                              unsigned short* __restrict__ wt_all,
                              unsigned short* __restrict__ wpt,
                              float* __restrict__ b_all) {
  int i = blockIdx.x * 256 + threadIdx.x;
  const int N1 = 1536 * 512;
  const int N2 = N1 + 512 * 512;
  const int N3 = N2 + 1536;
  if (i < N1) {
    int n = i >> 9, k = i & 511;
    float v = (n < 512) ? Wq[k * 512 + n] : Wkv[k * 1024 + (n - 512)];
    wt_all[n * 512 + k] = f2bf(v);
  } else if (i < N2) {
    int j = i - N1; int n = j >> 9, k = j & 511;
    wpt[n * 512 + k] = f2bf(Wp[k * 512 + n]);
  } else if (i < N3) {
    int n = i - N2;
    b_all[n] = (n < 512) ? bq[n] : bkv[n - 512];
  }
}

// ---------- kernels 3/5: bf16 MFMA GEMM, 128x128 tile, BK=32, double-buffered ----------
// A: [M][512] bf16 row-major.  Bt: [N][512] bf16 (transposed weights).
// Min-2-phase schedule: prefetch K-step kk+1 into buf^1 BEFORE ds_read+MFMA of buf,
// single barrier per K-step (its implicit vmcnt/lgkm drain orders both buffers).
template <int MODE>
__global__ __launch_bounds__(256) void gemm_kernel(
    const unsigned short* __restrict__ A, const unsigned short* __restrict__ Bt,
    const float* __restrict__ bias,
    unsigned short* __restrict__ qb, unsigned short* __restrict__ kb,
    unsigned short* __restrict__ vtb, float* __restrict__ outf) {
  __shared__ __align__(16) unsigned short lds_a[2][128 * 32];
  __shared__ __align__(16) unsigned short lds_b[2][128 * 32];
  const int tid = threadIdx.x;
  const int m0 = blockIdx.x * 128;
  const int n0 = blockIdx.y * 128;
  const int lane = tid & 63;
  const int wv = tid >> 6;
  const int wm = (wv >> 1) * 64, wn = (wv & 1) * 64;
  const int quad = lane >> 4, li = lane & 15;
  const int srow = tid >> 2, sq = (tid & 3) * 8;

  const unsigned short* ga = A + (size_t)(m0 + srow) * 512 + sq;
  const unsigned short* gb = Bt + (size_t)(n0 + srow) * 512 + sq;

  f32x4 acc[4][4];
#pragma unroll
  for (int i = 0; i < 4; i++)
#pragma unroll
    for (int j = 0; j < 4; j++) acc[i][j] = {0.f, 0.f, 0.f, 0.f};

  // prologue: stage K-step 0 into buffer 0
  {
    unsigned short* la = &lds_a[0][wv * 512];
    unsigned short* lb = &lds_b[0][wv * 512];
    gl_lds16(ga, la);
    gl_lds16(ga + 64 * 512, la + 2048);
    gl_lds16(gb, lb);
    gl_lds16(gb + 64 * 512, lb + 2048);
  }
  __syncthreads();   // drains vmcnt -> buf0 visible

#pragma unroll
  for (int kk = 0; kk < 16; kk++) {
    const int cur = kk & 1;
    // issue next K-step's staging first (overlaps with ds_read + MFMA below)
    if (kk < 15) {
      const int k1 = (kk + 1) * 32;
      unsigned short* la = &lds_a[cur ^ 1][wv * 512];
      unsigned short* lb = &lds_b[cur ^ 1][wv * 512];
      gl_lds16(ga + k1, la);
      gl_lds16(ga + 64 * 512 + k1, la + 2048);
      gl_lds16(gb + k1, lb);
      gl_lds16(gb + 64 * 512 + k1, lb + 2048);
    }
    bf16x8 af[4], bfr[4];
#pragma unroll
    for (int i = 0; i < 4; i++)
      af[i] = *(const bf16x8*)&lds_a[cur][(wm + i * 16 + li) * 32 + quad * 8];
#pragma unroll
    for (int j = 0; j < 4; j++)
      bfr[j] = *(const bf16x8*)&lds_b[cur][(wn + j * 16 + li) * 32 + quad * 8];
#pragma unroll
    for (int i = 0; i < 4; i++)
#pragma unroll
      for (int j = 0; j < 4; j++)
        acc[i][j] = mfma16(af[i], bfr[j], acc[i][j]);
    // one barrier per K-step: drains this step's reads of buf[cur] (so next
    // iteration may overwrite it) AND the prefetch into buf[cur^1] (vmcnt(0)).
    __syncthreads();
  }

  // epilogue: C/D layout col=lane&15, row=quad*4+reg
#pragma unroll
  for (int j = 0; j < 4; j++) {
    const int c = n0 + wn + j * 16 + li;
    const float badd = bias[c];
#pragma unroll
    for (int i = 0; i < 4; i++) {
      const int mb = m0 + wm + i * 16 + quad * 4;
#pragma unroll
      for (int r = 0; r < 4; r++) {
        const int m = mb + r;
        float v = acc[i][j][r] + badd;
        if (MODE == 1) {
          outf[(size_t)m * 512 + c] = v;
        } else {
          const int b = m >> 6, nn = m & 63;
          const int l = b >> 9, w = b & 511;
          const int seq = l * 64 + nn;
          const int d = c & 63;
          if (c < 512) {        // Q, fold softmax scale
            const int h = c >> 6;
            qb[((size_t)((w * 8 + h) * 192 + seq)) * 64 + d] = f2bf(v * SCALE_Q);
          } else if (c < 1024) {  // K
            const int h = (c - 512) >> 6;
            kb[((size_t)((w * 8 + h) * 192 + seq)) * 64 + d] = f2bf(v);
          } else {               // V transposed: [w][h][d][seq]
            const int h = (c - 1024) >> 6;
            vtb[((size_t)((w * 8 + h) * 64 + d)) * 192 + seq] = f2bf(v);
          }
        }
      }
    }
  }
}

// ---------- kernel 4: attention per (w, h, lq) — DIAGONAL BLOCK ONLY ----------
// MASK_FREQ adds -100 to every off-diagonal L-block logit; with in-block logits
// O(+-1), off-diagonal softmax weights are ~e^-98 (== 0 at fp32 precision).
// So attention is exactly block-diagonal: 64 keys per query block, not 192.
__global__ __launch_bounds__(256) void attn_kernel(
    const unsigned short* __restrict__ qb, const unsigned short* __restrict__ kb,
    const unsigned short* __restrict__ vtb, const float* __restrict__ bias_tables,
    unsigned short* __restrict__ ab) {
  const int w = blockIdx.x, h = blockIdx.y, lq = blockIdx.z;
  __shared__ float bias_l[225];
  __shared__ __align__(16) unsigned short lds_p[64 * 72];   // P, pitch 72 (=144B, 16B-mult)

  const int tid = threadIdx.x;
  // stage diagonal bias slice (lk == lq): 225 values for this head
  if (tid < 225) bias_l[tid] = bias_tables[((lq * 3 + lq) * 225 + tid) * 8 + h];
  __syncthreads();

  const int lane = tid & 63, wv = tid >> 6;
  const int quad = lane >> 4, li = lane & 15;
  const size_t base_qk = (size_t)(w * 8 + h) * 192 * 64;

  // q fragments (A-layout: m=li, k=quad*8+j), rows lq*64 + wv*16 + li
  const int qrow = lq * 64 + wv * 16 + li;
  bf16x8 aq0 = *(const bf16x8*)&qb[base_qk + (size_t)qrow * 64 + quad * 8];
  bf16x8 aq1 = *(const bf16x8*)&qb[base_qk + (size_t)qrow * 64 + 32 + quad * 8];

  // S = q @ k^T over the diagonal 64-key block: 4 n-tiles of 16 keys
  f32x4 s[4];
#pragma unroll
  for (int nt = 0; nt < 4; nt++) {
    const int krow = lq * 64 + nt * 16 + li;
    bf16x8 bk0 = *(const bf16x8*)&kb[base_qk + (size_t)krow * 64 + quad * 8];
    bf16x8 bk1 = *(const bf16x8*)&kb[base_qk + (size_t)krow * 64 + 32 + quad * 8];
    f32x4 a = {0.f, 0.f, 0.f, 0.f};
    a = mfma16(aq0, bk0, a);
    a = mfma16(aq1, bk1, a);
    s[nt] = a;
  }

  // + relative-position bias (no mask: diagonal block has mask 0)
#pragma unroll
  for (int nt = 0; nt < 4; nt++) {
    const int jj = nt * 16 + li;
    const int yj = jj >> 3, xj = jj & 7;
#pragma unroll
    for (int r = 0; r < 4; r++) {
      const int i = wv * 16 + quad * 4 + r;   // local q row in [0,64)
      const int yi = i >> 3, xi = i & 7;
      const int rel = (yi - yj + 7) * 15 + (xi - xj + 7);
      s[nt][r] += bias_l[rel];
    }
  }

  // softmax over 64 cols; lanes sharing a row are the 16 lanes of one quad
#pragma unroll
  for (int r = 0; r < 4; r++) {
    float m = -1e30f;
#pragma unroll
    for (int nt = 0; nt < 4; nt++) m = fmaxf(m, s[nt][r]);
#pragma unroll
    for (int off = 1; off < 16; off <<= 1) m = fmaxf(m, __shfl_xor(m, off, 64));
    float sum = 0.f;
#pragma unroll
    for (int nt = 0; nt < 4; nt++) { float e = __expf(s[nt][r] - m); s[nt][r] = e; sum += e; }
#pragma unroll
    for (int off = 1; off < 16; off <<= 1) sum += __shfl_xor(sum, off, 64);
    const float inv = 1.f / sum;
#pragma unroll
    for (int nt = 0; nt < 4; nt++) s[nt][r] *= inv;
  }

  // P (C-layout) -> LDS -> A-layout for PV
#pragma unroll
  for (int nt = 0; nt < 4; nt++)
#pragma unroll
    for (int r = 0; r < 4; r++)
      lds_p[(wv * 16 + quad * 4 + r) * 72 + nt * 16 + li] = f2bf(s[nt][r]);
  __syncthreads();

  // O = P @ V : K=64 over 2 k-steps, 4 d-tiles of 16 (diagonal seq slice of vtb)
  const size_t base_v = (size_t)(w * 8 + h) * 64 * 192;
  f32x4 o[4];
#pragma unroll
  for (int nt = 0; nt < 4; nt++) o[nt] = {0.f, 0.f, 0.f, 0.f};
#pragma unroll
  for (int ks = 0; ks < 2; ks++) {
    bf16x8 ap = *(const bf16x8*)&lds_p[(wv * 16 + li) * 72 + ks * 32 + quad * 8];
#pragma unroll
    for (int nt = 0; nt < 4; nt++) {
      bf16x8 bv = *(const bf16x8*)&vtb[base_v + (size_t)(nt * 16 + li) * 192 + lq * 64 + ks * 32 + quad * 8];
      o[nt] = mfma16(ap, bv, o[nt]);
    }
  }

  // store to attn_out in x-layout: row (lq*512+w)*64 + i, col h*64 + d
  const size_t mg_base = (size_t)(lq * 512 + w) * 64;
#pragma unroll
  for (int nt = 0; nt < 4; nt++) {
    const int col = h * 64 + nt * 16 + li;
#pragma unroll
    for (int r = 0; r < 4; r++) {
      const int i = wv * 16 + quad * 4 + r;
      ab[(mg_base + i) * 512 + col] = f2bf(o[nt][r]);
    }
  }
}

// ---------- launch ----------
extern "C" void kernel_launch(void* const* d_in, const int* in_sizes, int n_in,
                              void* d_out, int out_size, void* d_ws, size_t ws_size,
                              hipStream_t stream) {
  const float* x    = (const float*)d_in[0];
  const float* Wq   = (const float*)d_in[1];
  const float* bq   = (const float*)d_in[2];
  const float* Wkv  = (const float*)d_in[3];
  const float* bkv  = (const float*)d_in[4];
  const float* bt   = (const float*)d_in[5];
  const float* Wp   = (const float*)d_in[6];
  const float* bp   = (const float*)d_in[7];
  float* out = (float*)d_out;

  const long long SZ = 100663296LL;  // 98304*512*2 bytes
  char* ws = (char*)d_ws;
  unsigned short* xb     = (unsigned short*)(ws);
  unsigned short* qb     = (unsigned short*)(ws + 1 * SZ);
  unsigned short* kb     = (unsigned short*)(ws + 2 * SZ);
  unsigned short* vtb    = (unsigned short*)(ws + 3 * SZ);
  unsigned short* ab     = (unsigned short*)(ws + 4 * SZ);
  unsigned short* wt_all = (unsigned short*)(ws + 5 * SZ);
  unsigned short* wpt    = (unsigned short*)(ws + 5 * SZ + 1572864);
  float*          b_all  = (float*)(ws + 5 * SZ + 1572864 + 524288);

  convert_x_kernel<<<49152, 256, 0, stream>>>(x, xb);
  prep_w_kernel<<<4102, 256, 0, stream>>>(Wq, Wkv, bq, bkv, Wp, wt_all, wpt, b_all);
  gemm_kernel<0><<<dim3(768, 12), 256, 0, stream>>>(xb, wt_all, b_all, qb, kb, vtb, nullptr);
  attn_kernel<<<dim3(512, 8, 3), 256, 0, stream>>>(qb, kb, vtb, bt, ab);
  gemm_kernel<1><<<dim3(768, 4), 256, 0, stream>>>(ab, wpt, bp, nullptr, nullptr, nullptr, out);
}

// Round 2
// 893.295 us; speedup vs baseline: 1.2310x; 1.0076x over previous
//
#include <hip/hip_runtime.h>
#include <stdint.h>

// ---------- types ----------
typedef __bf16 bf16x8 __attribute__((ext_vector_type(8)));
typedef float f32x4 __attribute__((ext_vector_type(4)));

#define SCALE_Q 0.125f

// fp32 -> bf16 round-to-nearest-even
__device__ __forceinline__ unsigned short f2bf(float f) {
  unsigned int u = __float_as_uint(f);
  u = (u + 0x7fffu + ((u >> 16) & 1u)) >> 16;
  return (unsigned short)u;
}

// async global->LDS, 16B per lane. LDS dest = wave-uniform base + lane*16.
__device__ __forceinline__ void gl_lds16(const unsigned short* g, unsigned short* l) {
  __builtin_amdgcn_global_load_lds(
      (const __attribute__((address_space(1))) unsigned int*)g,
      (__attribute__((address_space(3))) unsigned int*)l, 16, 0, 0);
}

__device__ __forceinline__ f32x4 mfma16(bf16x8 a, bf16x8 b, f32x4 c) {
  return __builtin_amdgcn_mfma_f32_16x16x32_bf16(a, b, c, 0, 0, 0);
}

// ---------- kernel 1: x fp32 -> bf16 ----------
__global__ void convert_x_kernel(const float* __restrict__ x, unsigned short* __restrict__ xb) {
  int i = blockIdx.x * 256 + threadIdx.x;   // one float4 per thread, exact cover
  float4 f = ((const float4*)x)[i];
  ushort4 o;
  o.x = f2bf(f.x); o.y = f2bf(f.y); o.z = f2bf(f.z); o.w = f2bf(f.w);
  ((ushort4*)xb)[i] = o;
}

// ---------- kernel 2: pack transposed bf16 weights + bias ----------
__global__ void prep_w_kernel(const float* __restrict__ Wq, const float* __restrict__ Wkv,
                              const float* __restrict__ bq, const float* __restrict__ bkv,
                              const float* __restrict__ Wp,
                              unsigned short* __restrict__ wt_all,
                              unsigned short* __restrict__ wpt,
                              float* __restrict__ b_all) {
  int i = blockIdx.x * 256 + threadIdx.x;
  const int N1 = 1536 * 512;
  const int N2 = N1 + 512 * 512;
  const int N3 = N2 + 1536;
  if (i < N1) {
    int n = i >> 9, k = i & 511;
    float v = (n < 512) ? Wq[k * 512 + n] : Wkv[k * 1024 + (n - 512)];
    wt_all[n * 512 + k] = f2bf(v);
  } else if (i < N2) {
    int j = i - N1; int n = j >> 9, k = j & 511;
    wpt[n * 512 + k] = f2bf(Wp[k * 512 + n]);
  } else if (i < N3) {
    int n = i - N2;
    b_all[n] = (n < 512) ? bq[n] : bkv[n - 512];
  }
}

// ---------- kernels 3/5: bf16 MFMA GEMM, 128x128 tile, BK=32 ----------
// T4 counted-vmcnt pipeline: STAGE(kk+1) stays in flight ACROSS the raw
// s_barrier (no vmcnt(0) drain); wait vmcnt(4) only (= kk's loads landed).
// Grid: blockIdx.x = n-block (fastest) so all consumers of an A-tile are
// co-resident -> A reused from L2 instead of re-fetched from HBM.
template <int MODE>
__global__ __launch_bounds__(256) void gemm_kernel(
    const unsigned short* __restrict__ A, const unsigned short* __restrict__ Bt,
    const float* __restrict__ bias,
    unsigned short* __restrict__ qb, unsigned short* __restrict__ kb,
    unsigned short* __restrict__ vtb, float* __restrict__ outf) {
  __shared__ __align__(16) unsigned short lds_a[2][128 * 32];
  __shared__ __align__(16) unsigned short lds_b[2][128 * 32];
  const int tid = threadIdx.x;
  const int m0 = blockIdx.y * 128;   // m on y (slow)
  const int n0 = blockIdx.x * 128;   // n on x (fast) -> A-tile reuse in L2
  const int lane = tid & 63;
  const int wv = tid >> 6;
  const int wm = (wv >> 1) * 64, wn = (wv & 1) * 64;
  const int quad = lane >> 4, li = lane & 15;
  const int srow = tid >> 2, sq = (tid & 3) * 8;

  const unsigned short* ga = A + (size_t)(m0 + srow) * 512 + sq;
  const unsigned short* gb = Bt + (size_t)(n0 + srow) * 512 + sq;

  f32x4 acc[4][4];
#pragma unroll
  for (int i = 0; i < 4; i++)
#pragma unroll
    for (int j = 0; j < 4; j++) acc[i][j] = {0.f, 0.f, 0.f, 0.f};

  // prologue: stage K-step 0 into buffer 0 (4 loads in flight)
  {
    unsigned short* la = &lds_a[0][wv * 512];
    unsigned short* lb = &lds_b[0][wv * 512];
    gl_lds16(ga, la);
    gl_lds16(ga + 64 * 512, la + 2048);
    gl_lds16(gb, lb);
    gl_lds16(gb + 64 * 512, lb + 2048);
  }

#pragma unroll
  for (int kk = 0; kk < 16; kk++) {
    const int cur = kk & 1;
    // issue next K-step's staging first: these 4 loads fly across the barrier
    // and the whole MFMA phase (T4). Overwrite of buf[cur^1] is safe: its
    // readers finished before the previous iteration's trailing barrier.
    if (kk < 15) {
      const int k1 = (kk + 1) * 32;
      unsigned short* la = &lds_a[cur ^ 1][wv * 512];
      unsigned short* lb = &lds_b[cur ^ 1][wv * 512];
      gl_lds16(ga + k1, la);
      gl_lds16(ga + 64 * 512 + k1, la + 2048);
      gl_lds16(gb + k1, lb);
      gl_lds16(gb + 64 * 512 + k1, lb + 2048);
    }
    // wait only for kk's 4 loads (oldest); kk+1's 4 remain outstanding
    if (kk < 15) asm volatile("s_waitcnt vmcnt(4)" ::: "memory");
    else         asm volatile("s_waitcnt vmcnt(0)" ::: "memory");
    __builtin_amdgcn_s_barrier();   // all waves' kk loads visible in LDS
    bf16x8 af[4], bfr[4];
#pragma unroll
    for (int i = 0; i < 4; i++)
      af[i] = *(const bf16x8*)&lds_a[cur][(wm + i * 16 + li) * 32 + quad * 8];
#pragma unroll
    for (int j = 0; j < 4; j++)
      bfr[j] = *(const bf16x8*)&lds_b[cur][(wn + j * 16 + li) * 32 + quad * 8];
#pragma unroll
    for (int i = 0; i < 4; i++)
#pragma unroll
      for (int j = 0; j < 4; j++)
        acc[i][j] = mfma16(af[i], bfr[j], acc[i][j]);
    // trailing barrier: protects buf[cur] from next iteration's overwrite.
    // ds_reads are retired here (compiler waits lgkm before MFMA consumes).
    asm volatile("" ::: "memory");
    __builtin_amdgcn_s_barrier();
  }

  // epilogue: C/D layout col=lane&15, row=quad*4+reg
#pragma unroll
  for (int j = 0; j < 4; j++) {
    const int c = n0 + wn + j * 16 + li;
    const float badd = bias[c];
#pragma unroll
    for (int i = 0; i < 4; i++) {
      const int mb = m0 + wm + i * 16 + quad * 4;
#pragma unroll
      for (int r = 0; r < 4; r++) {
        const int m = mb + r;
        float v = acc[i][j][r] + badd;
        if (MODE == 1) {
          outf[(size_t)m * 512 + c] = v;
        } else {
          const int b = m >> 6, nn = m & 63;
          const int l = b >> 9, w = b & 511;
          const int seq = l * 64 + nn;
          const int d = c & 63;
          if (c < 512) {        // Q, fold softmax scale
            const int h = c >> 6;
            qb[((size_t)((w * 8 + h) * 192 + seq)) * 64 + d] = f2bf(v * SCALE_Q);
          } else if (c < 1024) {  // K
            const int h = (c - 512) >> 6;
            kb[((size_t)((w * 8 + h) * 192 + seq)) * 64 + d] = f2bf(v);
          } else {               // V transposed: [w][h][d][seq]
            const int h = (c - 1024) >> 6;
            vtb[((size_t)((w * 8 + h) * 64 + d)) * 192 + seq] = f2bf(v);
          }
        }
      }
    }
  }
}

// ---------- kernel 4: attention per (w, h, lq) — DIAGONAL BLOCK ONLY ----------
// MASK_FREQ adds -100 to every off-diagonal L-block logit; off-diagonal
// softmax weights are ~e^-98 == 0 at fp32 precision. Attention is exactly
// block-diagonal: 64 keys per query block.
__global__ __launch_bounds__(256) void attn_kernel(
    const unsigned short* __restrict__ qb, const unsigned short* __restrict__ kb,
    const unsigned short* __restrict__ vtb, const float* __restrict__ bias_tables,
    unsigned short* __restrict__ ab) {
  const int w = blockIdx.x, h = blockIdx.y, lq = blockIdx.z;
  __shared__ float bias_l[225];
  __shared__ __align__(16) unsigned short lds_p[64 * 72];   // P, pitch 72 (=144B, 16B-mult)

  const int tid = threadIdx.x;
  // stage diagonal bias slice (lk == lq): 225 values for this head
  if (tid < 225) bias_l[tid] = bias_tables[((lq * 3 + lq) * 225 + tid) * 8 + h];
  __syncthreads();

  const int lane = tid & 63, wv = tid >> 6;
  const int quad = lane >> 4, li = lane & 15;
  const size_t base_qk = (size_t)(w * 8 + h) * 192 * 64;

  // q fragments (A-layout: m=li, k=quad*8+j), rows lq*64 + wv*16 + li
  const int qrow = lq * 64 + wv * 16 + li;
  bf16x8 aq0 = *(const bf16x8*)&qb[base_qk + (size_t)qrow * 64 + quad * 8];
  bf16x8 aq1 = *(const bf16x8*)&qb[base_qk + (size_t)qrow * 64 + 32 + quad * 8];

  // S = q @ k^T over the diagonal 64-key block: 4 n-tiles of 16 keys
  f32x4 s[4];
#pragma unroll
  for (int nt = 0; nt < 4; nt++) {
    const int krow = lq * 64 + nt * 16 + li;
    bf16x8 bk0 = *(const bf16x8*)&kb[base_qk + (size_t)krow * 64 + quad * 8];
    bf16x8 bk1 = *(const bf16x8*)&kb[base_qk + (size_t)krow * 64 + 32 + quad * 8];
    f32x4 a = {0.f, 0.f, 0.f, 0.f};
    a = mfma16(aq0, bk0, a);
    a = mfma16(aq1, bk1, a);
    s[nt] = a;
  }

  // + relative-position bias (no mask: diagonal block has mask 0)
#pragma unroll
  for (int nt = 0; nt < 4; nt++) {
    const int jj = nt * 16 + li;
    const int yj = jj >> 3, xj = jj & 7;
#pragma unroll
    for (int r = 0; r < 4; r++) {
      const int i = wv * 16 + quad * 4 + r;   // local q row in [0,64)
      const int yi = i >> 3, xi = i & 7;
      const int rel = (yi - yj + 7) * 15 + (xi - xj + 7);
      s[nt][r] += bias_l[rel];
    }
  }

  // softmax over 64 cols; lanes sharing a row are the 16 lanes of one quad
#pragma unroll
  for (int r = 0; r < 4; r++) {
    float m = -1e30f;
#pragma unroll
    for (int nt = 0; nt < 4; nt++) m = fmaxf(m, s[nt][r]);
#pragma unroll
    for (int off = 1; off < 16; off <<= 1) m = fmaxf(m, __shfl_xor(m, off, 64));
    float sum = 0.f;
#pragma unroll
    for (int nt = 0; nt < 4; nt++) { float e = __expf(s[nt][r] - m); s[nt][r] = e; sum += e; }
#pragma unroll
    for (int off = 1; off < 16; off <<= 1) sum += __shfl_xor(sum, off, 64);
    const float inv = 1.f / sum;
#pragma unroll
    for (int nt = 0; nt < 4; nt++) s[nt][r] *= inv;
  }

  // P (C-layout) -> LDS -> A-layout for PV
#pragma unroll
  for (int nt = 0; nt < 4; nt++)
#pragma unroll
    for (int r = 0; r < 4; r++)
      lds_p[(wv * 16 + quad * 4 + r) * 72 + nt * 16 + li] = f2bf(s[nt][r]);
  __syncthreads();

  // O = P @ V : K=64 over 2 k-steps, 4 d-tiles of 16 (diagonal seq slice of vtb)
  const size_t base_v = (size_t)(w * 8 + h) * 64 * 192;
  f32x4 o[4];
#pragma unroll
  for (int nt = 0; nt < 4; nt++) o[nt] = {0.f, 0.f, 0.f, 0.f};
#pragma unroll
  for (int ks = 0; ks < 2; ks++) {
    bf16x8 ap = *(const bf16x8*)&lds_p[(wv * 16 + li) * 72 + ks * 32 + quad * 8];
#pragma unroll
    for (int nt = 0; nt < 4; nt++) {
      bf16x8 bv = *(const bf16x8*)&vtb[base_v + (size_t)(nt * 16 + li) * 192 + lq * 64 + ks * 32 + quad * 8];
      o[nt] = mfma16(ap, bv, o[nt]);
    }
  }

  // store to attn_out in x-layout: row (lq*512+w)*64 + i, col h*64 + d
  const size_t mg_base = (size_t)(lq * 512 + w) * 64;
#pragma unroll
  for (int nt = 0; nt < 4; nt++) {
    const int col = h * 64 + nt * 16 + li;
#pragma unroll
    for (int r = 0; r < 4; r++) {
      const int i = wv * 16 + quad * 4 + r;
      ab[(mg_base + i) * 512 + col] = f2bf(o[nt][r]);
    }
  }
}

// ---------- launch ----------
extern "C" void kernel_launch(void* const* d_in, const int* in_sizes, int n_in,
                              void* d_out, int out_size, void* d_ws, size_t ws_size,
                              hipStream_t stream) {
  const float* x    = (const float*)d_in[0];
  const float* Wq   = (const float*)d_in[1];
  const float* bq   = (const float*)d_in[2];
  const float* Wkv  = (const float*)d_in[3];
  const float* bkv  = (const float*)d_in[4];
  const float* bt   = (const float*)d_in[5];
  const float* Wp   = (const float*)d_in[6];
  const float* bp   = (const float*)d_in[7];
  float* out = (float*)d_out;

  const long long SZ = 100663296LL;  // 98304*512*2 bytes
  char* ws = (char*)d_ws;
  unsigned short* xb     = (unsigned short*)(ws);
  unsigned short* qb     = (unsigned short*)(ws + 1 * SZ);
  unsigned short* kb     = (unsigned short*)(ws + 2 * SZ);
  unsigned short* vtb    = (unsigned short*)(ws + 3 * SZ);
  unsigned short* ab     = (unsigned short*)(ws + 4 * SZ);
  unsigned short* wt_all = (unsigned short*)(ws + 5 * SZ);
  unsigned short* wpt    = (unsigned short*)(ws + 5 * SZ + 1572864);
  float*          b_all  = (float*)(ws + 5 * SZ + 1572864 + 524288);

  convert_x_kernel<<<49152, 256, 0, stream>>>(x, xb);
  prep_w_kernel<<<4102, 256, 0, stream>>>(Wq, Wkv, bq, bkv, Wp, wt_all, wpt, b_all);
  gemm_kernel<0><<<dim3(12, 768), 256, 0, stream>>>(xb, wt_all, b_all, qb, kb, vtb, nullptr);
  attn_kernel<<<dim3(512, 8, 3), 256, 0, stream>>>(qb, kb, vtb, bt, ab);
  gemm_kernel<1><<<dim3(4, 768), 256, 0, stream>>>(ab, wpt, bp, nullptr, nullptr, nullptr, out);
}